// Round 11
// baseline (433.974 us; speedup 1.0000x reference)
//
#include <hip/hip_runtime.h>
#include <math.h>

#define NN 50000
#define EE 800000
#define HH 64
#define RR 8
#define LL 3
#define NR (NN * RR)            // 400000 segments
#define NB ((NR + 255) / 256)   // 1563 scan blocks
#define LN_EPS 1e-5f
#define NEG_SLOPE 0.2f
#define LDH 68                  // LDS row stride (floats) for 16x64 fp32 tiles
#define PNB 584                 // ps node stride (bf16 units): 8*72 + 8 pad
#define OTB (16 * LDH)          // o-tile base inside ps_f
#define DSPREAD 64              // denom partial rows (distinct cachelines)

typedef __attribute__((ext_vector_type(8))) short bf8;
typedef __attribute__((ext_vector_type(4))) float f4;
typedef __attribute__((ext_vector_type(2))) float f2;
typedef __attribute__((ext_vector_type(4))) int i4;
typedef __attribute__((ext_vector_type(2))) unsigned int u2;

__device__ __forceinline__ unsigned short bf16r(float f) {
    unsigned u = __float_as_uint(f);
    unsigned r = u + 0x7fffu + ((u >> 16) & 1u);
    return (unsigned short)(r >> 16);
}
// 4 fp8 (one dword) dequant-FMA into fa[0..3]
__device__ __forceinline__ void fma_fp8x4(float* fa, int word, float a) {
    f2 lo = __builtin_amdgcn_cvt_pk_f32_fp8(word, false);
    f2 hi = __builtin_amdgcn_cvt_pk_f32_fp8(word, true);
    fa[0] += a * lo[0];
    fa[1] += a * lo[1];
    fa[2] += a * hi[0];
    fa[3] += a * hi[1];
}
// pack f4 -> 4 fp8 bytes
__device__ __forceinline__ int pk_fp8(f4 v) {
    int w = __builtin_amdgcn_cvt_pk_fp8_f32(v[0], v[1], 0, false);
    w = __builtin_amdgcn_cvt_pk_fp8_f32(v[2], v[3], w, true);
    return w;
}

// 16-node blocks: h = relu(x @ W_in^T + b_in) in fp32 via LDS;
// emit fp8 gather mirror; wave 0 computes s_src/s_dst via 2 MFMAs (WaB).
__global__ __launch_bounds__(256) void proj_in(
    const float* __restrict__ x, const float* __restrict__ W,
    const float* __restrict__ bias, const unsigned short* __restrict__ WaB,
    float* __restrict__ h, unsigned char* __restrict__ h8,
    float* __restrict__ s_src, float* __restrict__ s_dst) {
    __shared__ float WT[64 * LDH];     // WT[i][k] = W[k][i]
    __shared__ float xs[16 * LDH];
    __shared__ float hs[16 * LDH];
    int tid = threadIdx.x;
    int n0 = blockIdx.x * 16;          // NN % 16 == 0
    #pragma unroll
    for (int s = 0; s < 16; ++s) {
        int idx = tid + 256 * s;
        int k = idx >> 6, i = idx & 63;
        WT[i * LDH + k] = W[idx];
    }
    int row = tid >> 4, cg = tid & 15;
    {
        f4 v = ((const f4*)x)[(size_t)(n0 + row) * 16 + cg];
        *(f4*)&xs[row * LDH + cg * 4] = v;
    }
    __syncthreads();
    f4 acc;
    {
        f4 b = *(const f4*)(bias + cg * 4);
        acc = b;
        #pragma unroll
        for (int i = 0; i < 64; ++i) {
            float xv = xs[row * LDH + i];
            f4 wt = *(const f4*)&WT[i * LDH + cg * 4];
            acc[0] += xv * wt[0];
            acc[1] += xv * wt[1];
            acc[2] += xv * wt[2];
            acc[3] += xv * wt[3];
        }
        #pragma unroll
        for (int j = 0; j < 4; ++j) acc[j] = fmaxf(acc[j], 0.f);
        int n = n0 + row;
        *(f4*)(h + (size_t)n * 64 + cg * 4) = acc;
        *(int*)(h8 + (size_t)n * 64 + cg * 4) = pk_fp8(acc);
        *(f4*)&hs[row * LDH + cg * 4] = acc;
    }
    __syncthreads();
    if (tid < 64) {      // wave 0: attention pre-scores via MFMA
        int lane = tid;
        int quad = lane >> 4, lr = lane & 15;
        f4 sc = (f4){0.f, 0.f, 0.f, 0.f};
        #pragma unroll
        for (int kb = 0; kb < 2; ++kb) {
            const float* p = &hs[lr * LDH + kb * 32 + quad * 8];
            bf8 a;
            #pragma unroll
            for (int j = 0; j < 8; ++j) a[j] = (short)bf16r(p[j]);
            const bf8* bw = (const bf8*)(WaB + lr * 64 + kb * 32 + quad * 8);
            sc = __builtin_amdgcn_mfma_f32_16x16x32_bf16(a, *bw, sc, 0, 0, 0);
        }
        #pragma unroll
        for (int j = 0; j < 4; ++j) {
            int n = n0 + quad * 4 + j;
            if (lr < 8) s_src[n * 8 + lr] = sc[j];
            else        s_dst[n * 8 + (lr - 8)] = sc[j];
        }
    }
}

// ---- one-time CSR build (compact, exact) ----
__global__ void edge_count(const int* __restrict__ ei, const int* __restrict__ et,
                           int* __restrict__ counts, int* __restrict__ rank) {
    int e = blockIdx.x * 256 + threadIdx.x;
    int d = ei[EE + e], t = et[e];
    rank[e] = atomicAdd(&counts[d * 8 + t], 1);
}

__global__ void scan1(const int* __restrict__ counts, int* __restrict__ offs,
                      int* __restrict__ bsum) {
    __shared__ int s[256];
    int tid = threadIdx.x;
    int i = blockIdx.x * 256 + tid;
    int v = (i < NR) ? counts[i] : 0;
    s[tid] = v; __syncthreads();
    for (int d = 1; d < 256; d <<= 1) {
        int x = (tid >= d) ? s[tid - d] : 0;
        __syncthreads();
        s[tid] += x;
        __syncthreads();
    }
    if (i < NR) offs[i] = s[tid] - v;   // local (per-block) exclusive prefix
    if (tid == 255) bsum[blockIdx.x] = s[255];
}

__global__ void scan2(int* __restrict__ bsum) {   // 1024 threads, 2 chunks
    __shared__ int s[1024];
    int tid = threadIdx.x;
    int carry = 0;
    for (int c0 = 0; c0 < NB; c0 += 1024) {
        int i = c0 + tid;
        int v = (i < NB) ? bsum[i] : 0;
        s[tid] = v; __syncthreads();
        for (int d = 1; d < 1024; d <<= 1) {
            int x = (tid >= d) ? s[tid - d] : 0;
            __syncthreads();
            s[tid] += x;
            __syncthreads();
        }
        if (i < NB) bsum[i] = carry + s[tid] - v;
        int tot = s[1023];
        __syncthreads();
        carry += tot;
    }
}

// spack[slot] = {src, seg}; slot = offs[seg] + bsum[seg>>8] + rank
__global__ void edge_fill(const int* __restrict__ ei, const int* __restrict__ et,
                          const int* __restrict__ rank, const int* __restrict__ offs,
                          const int* __restrict__ bsum, u2* __restrict__ spack) {
    int e = blockIdx.x * 256 + threadIdx.x;
    int s = ei[e], d = ei[EE + e], t = et[e];
    int seg = d * 8 + t;
    int slot = offs[seg] + bsum[seg >> 8] + rank[e];
    spack[slot] = (u2){(unsigned)s, (unsigned)seg};
}

// weights -> bf16: WrB/WgB [r][kout][kd]; WaB [16][64]; WoB [kout][kd]
__global__ void cvt_w(const float* __restrict__ Wr, const float* __restrict__ Wg,
                      const float* __restrict__ Wa, const float* __restrict__ Wo,
                      unsigned short* __restrict__ WrB, unsigned short* __restrict__ WgB,
                      unsigned short* __restrict__ WaB, unsigned short* __restrict__ WoB) {
    int i = blockIdx.x * 256 + threadIdx.x;   // 32768 total
    WrB[i] = bf16r(Wr[i]);
    WgB[i] = bf16r(Wg[i]);
    if (i < 1024) {
        int row = i >> 6, k = i & 63;
        float v = (row < 8) ? Wa[row * 128 + k] : Wa[(row - 8) * 128 + 64 + k];
        WaB[i] = bf16r(v);
    }
    if (i < 4096) WoB[i] = bf16r(Wo[i]);
}

// slot-parallel softmax; epack[slot] = {src, ex}; per-type denom partials
// (no max subtraction: |score|<~8, fp32-safe; softmax ratio shift-invariant)
__global__ void edge_softmax2(const u2* __restrict__ spack,
                              const float* __restrict__ s_src, const float* __restrict__ s_dst,
                              const float* __restrict__ b_att,
                              u2* __restrict__ epack, float* __restrict__ dpart) {
    __shared__ float lsum[4][8];
    int tid = threadIdx.x;
    if (tid < 32) lsum[tid >> 3][tid & 7] = 0.f;
    __syncthreads();
    int slot = blockIdx.x * 256 + tid;     // EE % 256 == 0
    u2 sp = spack[slot];
    int src = (int)sp[0];
    int seg = (int)sp[1];
    int t = seg & 7;
    float sc = s_src[src * 8 + t] + s_dst[seg] + b_att[t];
    sc = (sc >= 0.f) ? sc : NEG_SLOPE * sc;
    float ex = __expf(sc);
    epack[slot] = (u2){(unsigned)src, __float_as_uint(ex)};
    atomicAdd(&lsum[tid >> 6][t], ex);
    __syncthreads();
    if (tid < 8) {
        float v = lsum[0][tid] + lsum[1][tid] + lsum[2][tid] + lsum[3][tid];
        atomicAdd(&dpart[(blockIdx.x & (DSPREAD - 1)) * 16 + tid], v);
    }
}

// Fused combine, 16-node tiles (NN % 16 == 0). Gather reads the fp8 mirror
// (64 B/row, 3.2 MB table -> per-XCD-L2 resident); A_h from fp32 hbuf
// (own rows, coalesced). Gather: one (node,r) segment per thread-pair,
// unroll-2, fp32 reg accumulate, bf16 LDS store; 8 barrier-free MFMA phases.
// EMIT: next-layer s_src/s_dst + fp8 mirror. OUT: final proj to outp
// (in-place safe: hbuf rows only read by the owning block before write).
template<bool EMIT, bool OUT>
__global__ __launch_bounds__(256, 8) void combine_fused(
    const float* __restrict__ hbuf, const unsigned char* __restrict__ h8_in,
    const int* __restrict__ offs, const int* __restrict__ bsum,
    const u2* __restrict__ epack, const float* __restrict__ dpartL,
    const unsigned short* __restrict__ WrB, const unsigned short* __restrict__ WgB,
    const unsigned short* __restrict__ WaB, const unsigned short* __restrict__ WoB,
    const float* __restrict__ b_gate, const float* __restrict__ gamma,
    const float* __restrict__ beta, float* __restrict__ hout,
    unsigned char* __restrict__ h8_out, float* __restrict__ ssrc_out,
    float* __restrict__ sdst_out, float* __restrict__ outp,
    const float* __restrict__ b_out) {
    __shared__ alignas(16) unsigned short ps[16 * PNB];   // bf16 pre-tile (18688 B)
    __shared__ float idn8[8];
    __shared__ int offsL[129];
    float* ps_f = (float*)ps;                             // fp32 reuse in epilogue
    int tid = threadIdx.x;
    int n0 = blockIdx.x * 16;

    if (tid < 129) {
        int sidx = n0 * 8 + tid;
        offsL[tid] = (sidx < NR) ? (offs[sidx] + bsum[sidx >> 8]) : EE;
    }
    if (tid >= 192) {   // wave 3: reduce denom partials -> idn8
        int t = tid & 7, g = (tid - 192) >> 3;
        float sm = 0.f;
        #pragma unroll
        for (int j = 0; j < 8; ++j) sm += dpartL[(g * 8 + j) * 16 + t];
        sm += __shfl_xor(sm, 8, 64);
        sm += __shfl_xor(sm, 16, 64);
        sm += __shfl_xor(sm, 32, 64);
        if ((tid & 63) < 8) idn8[t] = 1.f / sm;
    }
    __syncthreads();

    // ---- gather: segment-parallel, unroll-2, fp8 dequant, bf16 store ----
    {
        int segl = tid >> 1;            // local (node,r): 0..127
        int half = tid & 1;             // 32-col half
        int lo = offsL[segl], hi = offsL[segl + 1];
        int r = segl & 7;
        int gn = segl >> 3;
        float fa[32];
        #pragma unroll
        for (int j = 0; j < 32; ++j) fa[j] = 0.f;
        for (int s = lo; s < hi; s += 2) {
            u2 pk0 = epack[s];
            int s1 = (s + 1 < hi) ? (s + 1) : s;
            u2 pk1 = epack[s1];
            float a0 = __uint_as_float(pk0[1]);
            float a1 = (s + 1 < hi) ? __uint_as_float(pk1[1]) : 0.f;
            const i4* hp0 = (const i4*)(h8_in + ((size_t)(int)pk0[0] << 6) + half * 32);
            const i4* hp1 = (const i4*)(h8_in + ((size_t)(int)pk1[0] << 6) + half * 32);
            i4 v0a = hp0[0], v0b = hp0[1];
            i4 v1a = hp1[0], v1b = hp1[1];
            #pragma unroll
            for (int b = 0; b < 4; ++b) {
                fma_fp8x4(&fa[b * 4], v0a[b], a0);
                fma_fp8x4(&fa[16 + b * 4], v0b[b], a0);
                fma_fp8x4(&fa[b * 4], v1a[b], a1);
                fma_fp8x4(&fa[16 + b * 4], v1b[b], a1);
            }
        }
        float sA = idn8[r];
        unsigned short* pp = &ps[gn * PNB + r * 72 + half * 32];
        #pragma unroll
        for (int q = 0; q < 4; ++q) {
            __attribute__((ext_vector_type(8))) unsigned short o;
            #pragma unroll
            for (int j = 0; j < 8; ++j) o[j] = bf16r(fa[q * 8 + j] * sA);
            *(__attribute__((ext_vector_type(8))) unsigned short*)(pp + q * 8) = o;
        }
    }
    __syncthreads();

    int w = tid >> 6, lane = tid & 63;
    int quad = lane >> 4, lr = lane & 15;
    int tn = w;                       // this wave's 16 output cols

    // A_h fragments from fp32 hbuf (own rows, coalesced)
    bf8 a_h[2];
    #pragma unroll
    for (int kb = 0; kb < 2; ++kb) {
        const float* p = hbuf + ((size_t)(n0 + lr) << 6) + kb * 32 + quad * 8;
        bf8 a;
        #pragma unroll
        for (int j = 0; j < 8; ++j) a[j] = (short)bf16r(p[j]);
        a_h[kb] = a;
    }

    // ---- 8 relation MFMA phases ----
    f4 acc = (f4){0.f, 0.f, 0.f, 0.f};
    for (int r = 0; r < 8; ++r) {
        bf8 a_p[2];
        #pragma unroll
        for (int kb = 0; kb < 2; ++kb)
            a_p[kb] = *(const bf8*)&ps[lr * PNB + r * 72 + kb * 32 + quad * 8];
        f4 aggc = (f4){0.f, 0.f, 0.f, 0.f};
        f4 gacc = (f4){0.f, 0.f, 0.f, 0.f};
        #pragma unroll
        for (int kb = 0; kb < 2; ++kb) {
            const bf8* br = (const bf8*)(WrB + ((r * 64 + tn * 16 + lr) * 64 + kb * 32 + quad * 8));
            const bf8* bg = (const bf8*)(WgB + ((r * 64 + tn * 16 + lr) * 64 + kb * 32 + quad * 8));
            aggc = __builtin_amdgcn_mfma_f32_16x16x32_bf16(a_p[kb], *br, aggc, 0, 0, 0);
            gacc = __builtin_amdgcn_mfma_f32_16x16x32_bf16(a_h[kb], *bg, gacc, 0, 0, 0);
        }
        float bg = b_gate[r * 64 + tn * 16 + lr];
        #pragma unroll
        for (int j = 0; j < 4; ++j) {
            float g = 1.f / (1.f + __expf(-(gacc[j] + bg)));
            acc[j] += g * aggc[j];
        }
    }
    __syncthreads();   // ps fully consumed before fp32 reuse

    // t = h + acc/8 into ps_f (stride LDH), residual read from global
    #pragma unroll
    for (int j = 0; j < 4; ++j) {
        int row = quad * 4 + j;
        int col = tn * 16 + lr;
        ps_f[row * LDH + col] = hbuf[(size_t)(n0 + row) * 64 + col] + acc[j] * 0.125f;
    }
    __syncthreads();

    // LN + ReLU
    {
        int row = tid >> 4, c = tid & 15;
        int n = n0 + row;
        f4 tv = *(const f4*)&ps_f[row * LDH + c * 4];
        float s1 = tv[0] + tv[1] + tv[2] + tv[3];
        float s2 = tv[0]*tv[0] + tv[1]*tv[1] + tv[2]*tv[2] + tv[3]*tv[3];
        #pragma unroll
        for (int off = 1; off <= 8; off <<= 1) {
            s1 += __shfl_xor(s1, off, 64);
            s2 += __shfl_xor(s2, off, 64);
        }
        float mu = s1 * (1.f / 64.f);
        float var = s2 * (1.f / 64.f) - mu * mu;
        float rs = rsqrtf(var + LN_EPS);
        f4 g = *(const f4*)(gamma + c * 4);
        f4 b = *(const f4*)(beta + c * 4);
        f4 ov;
        #pragma unroll
        for (int j = 0; j < 4; ++j)
            ov[j] = fmaxf((tv[j] - mu) * rs * g[j] + b[j], 0.f);
        if (!OUT)
            *(f4*)(hout + (size_t)n * 64 + c * 4) = ov;
        __syncthreads();
        *(f4*)&ps_f[OTB + row * LDH + c * 4] = ov;   // o-tile (EMIT/OUT epilogues)
        if (EMIT)
            *(int*)(h8_out + (size_t)n * 64 + c * 4) = pk_fp8(ov);
    }

    if (EMIT) {
        __syncthreads();
        if (w == 0) {   // next-layer attention pre-scores
            f4 sc = (f4){0.f, 0.f, 0.f, 0.f};
            #pragma unroll
            for (int kb = 0; kb < 2; ++kb) {
                const float* p = &ps_f[OTB + lr * LDH + kb * 32 + quad * 8];
                bf8 a;
                #pragma unroll
                for (int j = 0; j < 8; ++j) a[j] = (short)bf16r(p[j]);
                const bf8* bw = (const bf8*)(WaB + lr * 64 + kb * 32 + quad * 8);
                sc = __builtin_amdgcn_mfma_f32_16x16x32_bf16(a, *bw, sc, 0, 0, 0);
            }
            #pragma unroll
            for (int j = 0; j < 4; ++j) {
                int n = n0 + quad * 4 + j;
                if (lr < 8) ssrc_out[n * 8 + lr] = sc[j];
                else        sdst_out[n * 8 + (lr - 8)] = sc[j];
            }
        }
    }

    if (OUT) {
        __syncthreads();
        f4 oc = (f4){0.f, 0.f, 0.f, 0.f};
        #pragma unroll
        for (int kb = 0; kb < 2; ++kb) {
            const float* p = &ps_f[OTB + lr * LDH + kb * 32 + quad * 8];
            bf8 a;
            #pragma unroll
            for (int j = 0; j < 8; ++j) a[j] = (short)bf16r(p[j]);
            const bf8* bw = (const bf8*)(WoB + ((tn * 16 + lr) * 64 + kb * 32 + quad * 8));
            oc = __builtin_amdgcn_mfma_f32_16x16x32_bf16(a, *bw, oc, 0, 0, 0);
        }
        float bo = b_out[tn * 16 + lr];
        #pragma unroll
        for (int j = 0; j < 4; ++j)
            outp[(size_t)(n0 + quad * 4 + j) * 64 + tn * 16 + lr] = oc[j] + bo;
    }
}

extern "C" void kernel_launch(void* const* d_in, const int* in_sizes, int n_in,
                              void* d_out, int out_size, void* d_ws, size_t ws_size,
                              hipStream_t stream) {
    const float* x      = (const float*)d_in[0];
    const int*   ei     = (const int*)d_in[1];
    const int*   et     = (const int*)d_in[2];
    const float* W_in   = (const float*)d_in[3];
    const float* b_in   = (const float*)d_in[4];
    const float* W_rel  = (const float*)d_in[5];
    const float* W_gate = (const float*)d_in[6];
    const float* b_gate = (const float*)d_in[7];
    const float* W_att  = (const float*)d_in[8];
    const float* b_att  = (const float*)d_in[9];
    const float* ln_g   = (const float*)d_in[10];
    const float* ln_b   = (const float*)d_in[11];
    const float* W_out  = (const float*)d_in[12];
    const float* b_out  = (const float*)d_in[13];
    float* out = (float*)d_out;

    float* h0 = (float*)d_out;          // ping-pong A (scratch until final layer)

    char* ws = (char*)d_ws;
    float* h1 = (float*)ws;                     ws += (size_t)NN * 64 * 4;
    unsigned char* h8A = (unsigned char*)ws;    ws += (size_t)NN * 64;
    unsigned char* h8B = (unsigned char*)ws;    ws += (size_t)NN * 64;
    float* s_src = (float*)ws;                  ws += (size_t)NN * 8 * 4;
    float* s_dst = (float*)ws;                  ws += (size_t)NN * 8 * 4;
    unsigned short* WrB = (unsigned short*)ws;  ws += (size_t)RR * 64 * 64 * 2;
    unsigned short* WgB = (unsigned short*)ws;  ws += (size_t)RR * 64 * 64 * 2;
    unsigned short* WaB = (unsigned short*)ws;  ws += 2048;
    unsigned short* WoB = (unsigned short*)ws;  ws += 8192;
    // contiguous zero region: counts + 3 per-layer dpart regions
    int* counts = (int*)ws;                     ws += (size_t)NR * 4;
    float* dpart = (float*)ws;                  ws += 3 * DSPREAD * 16 * 4;
    int* offs = (int*)ws;                       ws += (size_t)NR * 4;
    int* bsum = (int*)ws;                       ws += 6400;
    int* rank = (int*)ws;                       ws += (size_t)EE * 4;
    u2* spack = (u2*)ws;                        ws += (size_t)EE * 8;
    u2* epack = (u2*)ws;                        ws += (size_t)EE * 8;

    hipMemsetAsync(counts, 0, (size_t)NR * 4 + 3 * DSPREAD * 16 * 4, stream);
    cvt_w<<<128, 256, 0, stream>>>(W_rel, W_gate, W_att, W_out, WrB, WgB, WaB, WoB);
    edge_count<<<EE / 256, 256, 0, stream>>>(ei, et, counts, rank);
    scan1<<<NB, 256, 0, stream>>>(counts, offs, bsum);
    scan2<<<1, 1024, 0, stream>>>(bsum);
    edge_fill<<<EE / 256, 256, 0, stream>>>(ei, et, rank, offs, bsum, spack);
    proj_in<<<NN / 16, 256, 0, stream>>>(x, W_in, b_in, WaB, h0, h8A, s_src, s_dst);

    const int tiles16 = NN / 16;   // 3125, exact
    float* hA = h0;  float* hB = h1;
    unsigned char* bfA = h8A;  unsigned char* bfB = h8B;
    for (int layer = 0; layer < LL; ++layer) {
        float* dpl = dpart + (size_t)layer * DSPREAD * 16;
        edge_softmax2<<<EE / 256, 256, 0, stream>>>(spack, s_src, s_dst, b_att,
                                                    epack, dpl);
        if (layer < LL - 1) {
            combine_fused<true, false><<<tiles16, 256, 0, stream>>>(
                hA, bfA, offs, bsum, epack, dpl, WrB, WgB, WaB, WoB, b_gate,
                ln_g + layer * 64, ln_b + layer * 64,
                hB, bfB, s_src, s_dst, out, b_out);
        } else {
            combine_fused<false, true><<<tiles16, 256, 0, stream>>>(
                hA, bfA, offs, bsum, epack, dpl, WrB, WgB, WaB, WoB, b_gate,
                ln_g + layer * 64, ln_b + layer * 64,
                hB, bfB, s_src, s_dst, out, b_out);
        }
        float* tf = hA; hA = hB; hB = tf;
        unsigned char* tb = bfA; bfA = bfB; bfB = tb;
    }
}

// Round 12
// 421.778 us; speedup vs baseline: 1.0289x; 1.0289x over previous
//
#include <hip/hip_runtime.h>
#include <math.h>

#define NN 50000
#define EE 800000
#define HH 64
#define RR 8
#define LL 3
#define NR (NN * RR)            // 400000 segments
#define NB ((NR + 255) / 256)   // 1563 scan blocks
#define LN_EPS 1e-5f
#define NEG_SLOPE 0.2f
#define LDH 68                  // LDS row stride (floats) for 16x64 fp32 tiles
#define PNB 584                 // ps node stride (bf16 units): 8*72 + 8 pad
#define OTB (16 * LDH)          // o-tile base inside ps_f
#define DSPREAD 64              // denom partial rows (distinct cachelines)

typedef __attribute__((ext_vector_type(8))) short bf8;
typedef __attribute__((ext_vector_type(4))) float f4;
typedef __attribute__((ext_vector_type(8))) unsigned short us8;
typedef __attribute__((ext_vector_type(2))) unsigned int u2;

__device__ __forceinline__ unsigned short bf16r(float f) {
    unsigned u = __float_as_uint(f);
    unsigned r = u + 0x7fffu + ((u >> 16) & 1u);
    return (unsigned short)(r >> 16);
}
__device__ __forceinline__ float bf2f(unsigned short u) {
    return __uint_as_float(((unsigned)u) << 16);
}

// 16-node blocks: h = relu(x @ W_in^T + b_in) in fp32 via LDS;
// emit bf16 gather mirror; wave 0 computes s_src/s_dst via 2 MFMAs (WaB).
__global__ __launch_bounds__(256) void proj_in(
    const float* __restrict__ x, const float* __restrict__ W,
    const float* __restrict__ bias, const unsigned short* __restrict__ WaB,
    float* __restrict__ h, unsigned short* __restrict__ hbf,
    float* __restrict__ s_src, float* __restrict__ s_dst) {
    __shared__ float WT[64 * LDH];     // WT[i][k] = W[k][i]
    __shared__ float xs[16 * LDH];
    __shared__ float hs[16 * LDH];
    int tid = threadIdx.x;
    int n0 = blockIdx.x * 16;          // NN % 16 == 0
    #pragma unroll
    for (int s = 0; s < 16; ++s) {
        int idx = tid + 256 * s;
        int k = idx >> 6, i = idx & 63;
        WT[i * LDH + k] = W[idx];
    }
    int row = tid >> 4, cg = tid & 15;
    {
        f4 v = ((const f4*)x)[(size_t)(n0 + row) * 16 + cg];
        *(f4*)&xs[row * LDH + cg * 4] = v;
    }
    __syncthreads();
    f4 acc;
    {
        f4 b = *(const f4*)(bias + cg * 4);
        acc = b;
        #pragma unroll
        for (int i = 0; i < 64; ++i) {
            float xv = xs[row * LDH + i];
            f4 wt = *(const f4*)&WT[i * LDH + cg * 4];
            acc[0] += xv * wt[0];
            acc[1] += xv * wt[1];
            acc[2] += xv * wt[2];
            acc[3] += xv * wt[3];
        }
        #pragma unroll
        for (int j = 0; j < 4; ++j) acc[j] = fmaxf(acc[j], 0.f);
        int n = n0 + row;
        *(f4*)(h + (size_t)n * 64 + cg * 4) = acc;
        u2 u;
        u[0] = (unsigned)bf16r(acc[0]) | ((unsigned)bf16r(acc[1]) << 16);
        u[1] = (unsigned)bf16r(acc[2]) | ((unsigned)bf16r(acc[3]) << 16);
        *(u2*)(hbf + (size_t)n * 64 + cg * 4) = u;
        *(f4*)&hs[row * LDH + cg * 4] = acc;
    }
    __syncthreads();
    if (tid < 64) {      // wave 0: attention pre-scores via MFMA
        int lane = tid;
        int quad = lane >> 4, lr = lane & 15;
        f4 sc = (f4){0.f, 0.f, 0.f, 0.f};
        #pragma unroll
        for (int kb = 0; kb < 2; ++kb) {
            const float* p = &hs[lr * LDH + kb * 32 + quad * 8];
            bf8 a;
            #pragma unroll
            for (int j = 0; j < 8; ++j) a[j] = (short)bf16r(p[j]);
            const bf8* bw = (const bf8*)(WaB + lr * 64 + kb * 32 + quad * 8);
            sc = __builtin_amdgcn_mfma_f32_16x16x32_bf16(a, *bw, sc, 0, 0, 0);
        }
        #pragma unroll
        for (int j = 0; j < 4; ++j) {
            int n = n0 + quad * 4 + j;
            if (lr < 8) s_src[n * 8 + lr] = sc[j];
            else        s_dst[n * 8 + (lr - 8)] = sc[j];
        }
    }
}

// ---- one-time CSR build (compact, exact) ----
__global__ void edge_count(const int* __restrict__ ei, const int* __restrict__ et,
                           int* __restrict__ counts, int* __restrict__ rank) {
    int e = blockIdx.x * 256 + threadIdx.x;
    int d = ei[EE + e], t = et[e];
    rank[e] = atomicAdd(&counts[d * 8 + t], 1);
}

__global__ void scan1(const int* __restrict__ counts, int* __restrict__ offs,
                      int* __restrict__ bsum) {
    __shared__ int s[256];
    int tid = threadIdx.x;
    int i = blockIdx.x * 256 + tid;
    int v = (i < NR) ? counts[i] : 0;
    s[tid] = v; __syncthreads();
    for (int d = 1; d < 256; d <<= 1) {
        int x = (tid >= d) ? s[tid - d] : 0;
        __syncthreads();
        s[tid] += x;
        __syncthreads();
    }
    if (i < NR) offs[i] = s[tid] - v;   // local (per-block) exclusive prefix
    if (tid == 255) bsum[blockIdx.x] = s[255];
}

__global__ void scan2(int* __restrict__ bsum) {   // 1024 threads, 2 chunks
    __shared__ int s[1024];
    int tid = threadIdx.x;
    int carry = 0;
    for (int c0 = 0; c0 < NB; c0 += 1024) {
        int i = c0 + tid;
        int v = (i < NB) ? bsum[i] : 0;
        s[tid] = v; __syncthreads();
        for (int d = 1; d < 1024; d <<= 1) {
            int x = (tid >= d) ? s[tid - d] : 0;
            __syncthreads();
            s[tid] += x;
            __syncthreads();
        }
        if (i < NB) bsum[i] = carry + s[tid] - v;
        int tot = s[1023];
        __syncthreads();
        carry += tot;
    }
}

// spack[slot] = {src, seg}; slot = offs[seg] + bsum[seg>>8] + rank
__global__ void edge_fill(const int* __restrict__ ei, const int* __restrict__ et,
                          const int* __restrict__ rank, const int* __restrict__ offs,
                          const int* __restrict__ bsum, u2* __restrict__ spack) {
    int e = blockIdx.x * 256 + threadIdx.x;
    int s = ei[e], d = ei[EE + e], t = et[e];
    int seg = d * 8 + t;
    int slot = offs[seg] + bsum[seg >> 8] + rank[e];
    spack[slot] = (u2){(unsigned)s, (unsigned)seg};
}

// weights -> bf16: WrB/WgB [r][kout][kd]; WaB [16][64]; WoB [kout][kd]
__global__ void cvt_w(const float* __restrict__ Wr, const float* __restrict__ Wg,
                      const float* __restrict__ Wa, const float* __restrict__ Wo,
                      unsigned short* __restrict__ WrB, unsigned short* __restrict__ WgB,
                      unsigned short* __restrict__ WaB, unsigned short* __restrict__ WoB) {
    int i = blockIdx.x * 256 + threadIdx.x;   // 32768 total
    WrB[i] = bf16r(Wr[i]);
    WgB[i] = bf16r(Wg[i]);
    if (i < 1024) {
        int row = i >> 6, k = i & 63;
        float v = (row < 8) ? Wa[row * 128 + k] : Wa[(row - 8) * 128 + 64 + k];
        WaB[i] = bf16r(v);
    }
    if (i < 4096) WoB[i] = bf16r(Wo[i]);
}

// slot-parallel softmax; epack[slot] = {src, ex}; per-type denom partials
// (no max subtraction: |score|<~8, fp32-safe; softmax ratio shift-invariant)
__global__ void edge_softmax2(const u2* __restrict__ spack,
                              const float* __restrict__ s_src, const float* __restrict__ s_dst,
                              const float* __restrict__ b_att,
                              u2* __restrict__ epack, float* __restrict__ dpart) {
    __shared__ float lsum[4][8];
    int tid = threadIdx.x;
    if (tid < 32) lsum[tid >> 3][tid & 7] = 0.f;
    __syncthreads();
    int slot = blockIdx.x * 256 + tid;     // EE % 256 == 0
    u2 sp = spack[slot];
    int src = (int)sp[0];
    int seg = (int)sp[1];
    int t = seg & 7;
    float sc = s_src[src * 8 + t] + s_dst[seg] + b_att[t];
    sc = (sc >= 0.f) ? sc : NEG_SLOPE * sc;
    float ex = __expf(sc);
    epack[slot] = (u2){(unsigned)src, __float_as_uint(ex)};
    atomicAdd(&lsum[tid >> 6][t], ex);
    __syncthreads();
    if (tid < 8) {
        float v = lsum[0][tid] + lsum[1][tid] + lsum[2][tid] + lsum[3][tid];
        atomicAdd(&dpart[(blockIdx.x & (DSPREAD - 1)) * 16 + tid], v);
    }
}

// Fused combine, 16-node tiles (NN % 16 == 0). Staged fp32 hs tile (LDS);
// gather from bf16 mirror, one (node,r) segment per thread-pair, unroll-2,
// fp32 reg accumulate, bf16 LDS store; 8 barrier-free MFMA relation phases.
// EMIT: next-layer s_src/s_dst (MFMA vs WaB) + bf16 mirror.
// OUT: final proj o @ W_out^T + b_out -> outp (in-place safe: hbuf rows read
// only by the owning block, and only before its writes).
template<bool EMIT, bool OUT>
__global__ __launch_bounds__(256, 6) void combine_fused(
    const float* __restrict__ hbuf, const unsigned short* __restrict__ hbf_in,
    const int* __restrict__ offs, const int* __restrict__ bsum,
    const u2* __restrict__ epack, const float* __restrict__ dpartL,
    const unsigned short* __restrict__ WrB, const unsigned short* __restrict__ WgB,
    const unsigned short* __restrict__ WaB, const unsigned short* __restrict__ WoB,
    const float* __restrict__ b_gate, const float* __restrict__ gamma,
    const float* __restrict__ beta, float* __restrict__ hout,
    unsigned short* __restrict__ hbf_out, float* __restrict__ ssrc_out,
    float* __restrict__ sdst_out, float* __restrict__ outp,
    const float* __restrict__ b_out) {
    __shared__ float hs[16 * LDH];
    __shared__ alignas(16) unsigned short ps[16 * PNB];   // bf16 pre-tile (18688 B)
    __shared__ float idn8[8];
    __shared__ int offsL[129];
    float* ps_f = (float*)ps;                             // fp32 reuse in epilogue
    int tid = threadIdx.x;
    int n0 = blockIdx.x * 16;

    // stage h tile (fp32), one float4 per thread
    {
        int row = tid >> 4, c4 = tid & 15;
        f4 v = ((const f4*)hbuf)[(size_t)(n0 + row) * 16 + c4];
        *(f4*)&hs[row * LDH + c4 * 4] = v;
    }
    if (tid < 129) {
        int sidx = n0 * 8 + tid;
        offsL[tid] = (sidx < NR) ? (offs[sidx] + bsum[sidx >> 8]) : EE;
    }
    if (tid >= 192) {   // wave 3: reduce denom partials -> idn8
        int t = tid & 7, g = (tid - 192) >> 3;
        float sm = 0.f;
        #pragma unroll
        for (int j = 0; j < 8; ++j) sm += dpartL[(g * 8 + j) * 16 + t];
        sm += __shfl_xor(sm, 8, 64);
        sm += __shfl_xor(sm, 16, 64);
        sm += __shfl_xor(sm, 32, 64);
        if ((tid & 63) < 8) idn8[t] = 1.f / sm;
    }
    __syncthreads();

    // ---- gather: segment-parallel, unroll-2, register accumulate, bf16 store ----
    {
        int segl = tid >> 1;            // local (node,r): 0..127
        int half = tid & 1;             // 32-col half
        int lo = offsL[segl], hi = offsL[segl + 1];
        int r = segl & 7;
        int gn = segl >> 3;
        float fa[32];
        #pragma unroll
        for (int j = 0; j < 32; ++j) fa[j] = 0.f;
        for (int s = lo; s < hi; s += 2) {
            u2 pk0 = epack[s];
            int s1 = (s + 1 < hi) ? (s + 1) : s;
            u2 pk1 = epack[s1];
            float a0 = __uint_as_float(pk0[1]);
            float a1 = (s + 1 < hi) ? __uint_as_float(pk1[1]) : 0.f;
            const us8* hp0 = (const us8*)(hbf_in + ((size_t)(int)pk0[0] << 6) + half * 32);
            const us8* hp1 = (const us8*)(hbf_in + ((size_t)(int)pk1[0] << 6) + half * 32);
            #pragma unroll
            for (int q = 0; q < 4; ++q) {
                us8 v0 = hp0[q];
                us8 v1 = hp1[q];
                #pragma unroll
                for (int j = 0; j < 8; ++j) {
                    fa[q * 8 + j] += a0 * bf2f(v0[j]);
                    fa[q * 8 + j] += a1 * bf2f(v1[j]);
                }
            }
        }
        float sA = idn8[r];
        unsigned short* pp = &ps[gn * PNB + r * 72 + half * 32];
        #pragma unroll
        for (int q = 0; q < 4; ++q) {
            us8 o;
            #pragma unroll
            for (int j = 0; j < 8; ++j) o[j] = bf16r(fa[q * 8 + j] * sA);
            *(us8*)(pp + q * 8) = o;
        }
    }
    __syncthreads();

    int w = tid >> 6, lane = tid & 63;
    int quad = lane >> 4, lr = lane & 15;
    int tn = w;                       // this wave's 16 output cols

    // A_h fragments from staged hs
    bf8 a_h[2];
    #pragma unroll
    for (int kb = 0; kb < 2; ++kb) {
        const float* p = &hs[lr * LDH + kb * 32 + quad * 8];
        bf8 a;
        #pragma unroll
        for (int j = 0; j < 8; ++j) a[j] = (short)bf16r(p[j]);
        a_h[kb] = a;
    }

    // ---- 8 relation MFMA phases ----
    f4 acc = (f4){0.f, 0.f, 0.f, 0.f};
    for (int r = 0; r < 8; ++r) {
        bf8 a_p[2];
        #pragma unroll
        for (int kb = 0; kb < 2; ++kb)
            a_p[kb] = *(const bf8*)&ps[lr * PNB + r * 72 + kb * 32 + quad * 8];
        f4 aggc = (f4){0.f, 0.f, 0.f, 0.f};
        f4 gacc = (f4){0.f, 0.f, 0.f, 0.f};
        #pragma unroll
        for (int kb = 0; kb < 2; ++kb) {
            const bf8* br = (const bf8*)(WrB + ((r * 64 + tn * 16 + lr) * 64 + kb * 32 + quad * 8));
            const bf8* bg = (const bf8*)(WgB + ((r * 64 + tn * 16 + lr) * 64 + kb * 32 + quad * 8));
            aggc = __builtin_amdgcn_mfma_f32_16x16x32_bf16(a_p[kb], *br, aggc, 0, 0, 0);
            gacc = __builtin_amdgcn_mfma_f32_16x16x32_bf16(a_h[kb], *bg, gacc, 0, 0, 0);
        }
        float bg = b_gate[r * 64 + tn * 16 + lr];
        #pragma unroll
        for (int j = 0; j < 4; ++j) {
            float g = 1.f / (1.f + __expf(-(gacc[j] + bg)));
            acc[j] += g * aggc[j];
        }
    }
    __syncthreads();   // ps fully consumed before fp32 reuse

    // t = h + acc/8 into ps_f (stride LDH), residual from staged hs
    #pragma unroll
    for (int j = 0; j < 4; ++j) {
        int row = quad * 4 + j;
        int col = tn * 16 + lr;
        ps_f[row * LDH + col] = hs[row * LDH + col] + acc[j] * 0.125f;
    }
    __syncthreads();

    // LN + ReLU; o-tile into ps_f[OTB..) (disjoint region, no barrier needed)
    {
        int row = tid >> 4, c = tid & 15;
        int n = n0 + row;
        f4 tv = *(const f4*)&ps_f[row * LDH + c * 4];
        float s1 = tv[0] + tv[1] + tv[2] + tv[3];
        float s2 = tv[0]*tv[0] + tv[1]*tv[1] + tv[2]*tv[2] + tv[3]*tv[3];
        #pragma unroll
        for (int off = 1; off <= 8; off <<= 1) {
            s1 += __shfl_xor(s1, off, 64);
            s2 += __shfl_xor(s2, off, 64);
        }
        float mu = s1 * (1.f / 64.f);
        float var = s2 * (1.f / 64.f) - mu * mu;
        float rs = rsqrtf(var + LN_EPS);
        f4 g = *(const f4*)(gamma + c * 4);
        f4 b = *(const f4*)(beta + c * 4);
        f4 ov;
        #pragma unroll
        for (int j = 0; j < 4; ++j)
            ov[j] = fmaxf((tv[j] - mu) * rs * g[j] + b[j], 0.f);
        if (!OUT)
            *(f4*)(hout + (size_t)n * 64 + c * 4) = ov;
        *(f4*)&ps_f[OTB + row * LDH + c * 4] = ov;
        if (EMIT) {
            u2 u;
            u[0] = (unsigned)bf16r(ov[0]) | ((unsigned)bf16r(ov[1]) << 16);
            u[1] = (unsigned)bf16r(ov[2]) | ((unsigned)bf16r(ov[3]) << 16);
            *(u2*)(hbf_out + (size_t)n * 64 + c * 4) = u;
        }
    }

    if (EMIT) {
        __syncthreads();
        if (w == 0) {   // next-layer attention pre-scores
            f4 sc = (f4){0.f, 0.f, 0.f, 0.f};
            #pragma unroll
            for (int kb = 0; kb < 2; ++kb) {
                const float* p = &ps_f[OTB + lr * LDH + kb * 32 + quad * 8];
                bf8 a;
                #pragma unroll
                for (int j = 0; j < 8; ++j) a[j] = (short)bf16r(p[j]);
                const bf8* bw = (const bf8*)(WaB + lr * 64 + kb * 32 + quad * 8);
                sc = __builtin_amdgcn_mfma_f32_16x16x32_bf16(a, *bw, sc, 0, 0, 0);
            }
            #pragma unroll
            for (int j = 0; j < 4; ++j) {
                int n = n0 + quad * 4 + j;
                if (lr < 8) ssrc_out[n * 8 + lr] = sc[j];
                else        sdst_out[n * 8 + (lr - 8)] = sc[j];
            }
        }
    }

    if (OUT) {
        __syncthreads();
        f4 oc = (f4){0.f, 0.f, 0.f, 0.f};
        #pragma unroll
        for (int kb = 0; kb < 2; ++kb) {
            const float* p = &ps_f[OTB + lr * LDH + kb * 32 + quad * 8];
            bf8 a;
            #pragma unroll
            for (int j = 0; j < 8; ++j) a[j] = (short)bf16r(p[j]);
            const bf8* bw = (const bf8*)(WoB + ((tn * 16 + lr) * 64 + kb * 32 + quad * 8));
            oc = __builtin_amdgcn_mfma_f32_16x16x32_bf16(a, *bw, oc, 0, 0, 0);
        }
        float bo = b_out[tn * 16 + lr];
        #pragma unroll
        for (int j = 0; j < 4; ++j)
            outp[(size_t)(n0 + quad * 4 + j) * 64 + tn * 16 + lr] = oc[j] + bo;
    }
}

extern "C" void kernel_launch(void* const* d_in, const int* in_sizes, int n_in,
                              void* d_out, int out_size, void* d_ws, size_t ws_size,
                              hipStream_t stream) {
    const float* x      = (const float*)d_in[0];
    const int*   ei     = (const int*)d_in[1];
    const int*   et     = (const int*)d_in[2];
    const float* W_in   = (const float*)d_in[3];
    const float* b_in   = (const float*)d_in[4];
    const float* W_rel  = (const float*)d_in[5];
    const float* W_gate = (const float*)d_in[6];
    const float* b_gate = (const float*)d_in[7];
    const float* W_att  = (const float*)d_in[8];
    const float* b_att  = (const float*)d_in[9];
    const float* ln_g   = (const float*)d_in[10];
    const float* ln_b   = (const float*)d_in[11];
    const float* W_out  = (const float*)d_in[12];
    const float* b_out  = (const float*)d_in[13];
    float* out = (float*)d_out;

    float* h0 = (float*)d_out;          // ping-pong A (scratch until final layer)

    char* ws = (char*)d_ws;
    float* h1 = (float*)ws;                     ws += (size_t)NN * 64 * 4;
    unsigned short* hbfA = (unsigned short*)ws; ws += (size_t)NN * 64 * 2;
    unsigned short* hbfB = (unsigned short*)ws; ws += (size_t)NN * 64 * 2;
    float* s_src = (float*)ws;                  ws += (size_t)NN * 8 * 4;
    float* s_dst = (float*)ws;                  ws += (size_t)NN * 8 * 4;
    unsigned short* WrB = (unsigned short*)ws;  ws += (size_t)RR * 64 * 64 * 2;
    unsigned short* WgB = (unsigned short*)ws;  ws += (size_t)RR * 64 * 64 * 2;
    unsigned short* WaB = (unsigned short*)ws;  ws += 2048;
    unsigned short* WoB = (unsigned short*)ws;  ws += 8192;
    // contiguous zero region: counts + 3 per-layer dpart regions
    int* counts = (int*)ws;                     ws += (size_t)NR * 4;
    float* dpart = (float*)ws;                  ws += 3 * DSPREAD * 16 * 4;
    int* offs = (int*)ws;                       ws += (size_t)NR * 4;
    int* bsum = (int*)ws;                       ws += 6400;
    int* rank = (int*)ws;                       ws += (size_t)EE * 4;
    u2* spack = (u2*)ws;                        ws += (size_t)EE * 8;
    u2* epack = (u2*)ws;                        ws += (size_t)EE * 8;

    hipMemsetAsync(counts, 0, (size_t)NR * 4 + 3 * DSPREAD * 16 * 4, stream);
    cvt_w<<<128, 256, 0, stream>>>(W_rel, W_gate, W_att, W_out, WrB, WgB, WaB, WoB);
    edge_count<<<EE / 256, 256, 0, stream>>>(ei, et, counts, rank);
    scan1<<<NB, 256, 0, stream>>>(counts, offs, bsum);
    scan2<<<1, 1024, 0, stream>>>(bsum);
    edge_fill<<<EE / 256, 256, 0, stream>>>(ei, et, rank, offs, bsum, spack);
    proj_in<<<NN / 16, 256, 0, stream>>>(x, W_in, b_in, WaB, h0, hbfA, s_src, s_dst);

    const int tiles16 = NN / 16;   // 3125, exact
    float* hA = h0;  float* hB = h1;
    unsigned short* bfA = hbfA;  unsigned short* bfB = hbfB;
    for (int layer = 0; layer < LL; ++layer) {
        float* dpl = dpart + (size_t)layer * DSPREAD * 16;
        edge_softmax2<<<EE / 256, 256, 0, stream>>>(spack, s_src, s_dst, b_att,
                                                    epack, dpl);
        if (layer < LL - 1) {
            combine_fused<true, false><<<tiles16, 256, 0, stream>>>(
                hA, bfA, offs, bsum, epack, dpl, WrB, WgB, WaB, WoB, b_gate,
                ln_g + layer * 64, ln_b + layer * 64,
                hB, bfB, s_src, s_dst, out, b_out);
        } else {
            combine_fused<false, true><<<tiles16, 256, 0, stream>>>(
                hA, bfA, offs, bsum, epack, dpl, WrB, WgB, WaB, WoB, b_gate,
                ln_g + layer * 64, ln_b + layer * 64,
                hB, bfB, s_src, s_dst, out, b_out);
        }
        float* tf = hA; hA = hB; hB = tf;
        unsigned short* tb = bfA; bfA = bfB; bfB = tb;
    }
}